// Round 10
// baseline (309.552 us; speedup 1.0000x reference)
//
#include <hip/hip_runtime.h>
#include <hip/hip_bf16.h>

// GCN: out[i] = deg_i * sum_{j in N(i)} deg_j * (X@W)[j]
// FUSED single kernel, 768 co-resident blocks (4/CU capacity, 25% margin):
//   phase 1: R9 GEMM body (W->LDS bf16 transposed, 2x8 pipelined X loads,
//            operand-swapped MFMA, fused deg_j, bf16 Xp), grid-stride tiles
//   device-wide software barrier (agent-scope atomics + fences)
//   phase 2: R7 agg body (8 lanes/node, 16-edge fast path), grid-stride
// Barrier counter zeroed per launch via hipMemsetAsync (capture-safe).

constexpr int D_IN  = 256;
constexpr int D_OUT = 64;
constexpr int WT_LD = D_IN + 8;
constexpr int NBLK  = 768;

typedef short  s8v  __attribute__((ext_vector_type(8)));
typedef __bf16 bf8v __attribute__((ext_vector_type(8)));
typedef float  f32x4 __attribute__((ext_vector_type(4)));
typedef unsigned short us8v __attribute__((ext_vector_type(8)));

union BF8 { bf8v b; s8v s; };

__global__ __launch_bounds__(256, 4) void fused_gcn_kernel(
    const float* __restrict__ X, const float* __restrict__ W,
    const int* __restrict__ rp, const int* __restrict__ ci,
    const float* __restrict__ deg, unsigned short* __restrict__ Xp,
    float* __restrict__ out, unsigned int* __restrict__ bar,
    int n, int ntiles)
{
    __shared__ __bf16 Wt[D_OUT][WT_LD];

    const int tid = threadIdx.x;

    // ---- phase 1: GEMM ----
    #pragma unroll
    for (int i = 0; i < 16; ++i) {
        const int f4 = tid + i * 256;
        const int k  = f4 >> 4;
        const int c4 = (f4 & 15) * 4;
        const float4 w = *reinterpret_cast<const float4*>(&W[(size_t)k * D_OUT + c4]);
        Wt[c4 + 0][k] = (__bf16)w.x;
        Wt[c4 + 1][k] = (__bf16)w.y;
        Wt[c4 + 2][k] = (__bf16)w.z;
        Wt[c4 + 3][k] = (__bf16)w.w;
    }
    __syncthreads();

    const int wid  = tid >> 6;
    const int lane = tid & 63;
    const int lrow = lane & 15;
    const int kgrp = lane >> 4;

    const __bf16* wt0 = &Wt[lrow][kgrp * 8];
    const int wstride = gridDim.x << 2;

    for (int tile = blockIdx.x * 4 + wid; tile < ntiles; tile += wstride) {
        const int grow = tile * 16 + lrow;
        const int xr   = grow < n ? grow : n - 1;
        const float* xrow = X + (size_t)xr * D_IN + kgrp * 8;

        float4 xa[8], xb[8];
        #pragma unroll
        for (int k = 0; k < 4; ++k) {
            xa[2 * k]     = *reinterpret_cast<const float4*>(xrow + k * 32);
            xa[2 * k + 1] = *reinterpret_cast<const float4*>(xrow + k * 32 + 4);
        }
        #pragma unroll
        for (int k = 0; k < 4; ++k) {
            xb[2 * k]     = *reinterpret_cast<const float4*>(xrow + (k + 4) * 32);
            xb[2 * k + 1] = *reinterpret_cast<const float4*>(xrow + (k + 4) * 32 + 4);
        }

        f32x4 acc[4] = {};

        #pragma unroll
        for (int ks = 0; ks < 4; ++ks) {
            BF8 xf;
            const float4 x0 = xa[2 * ks];
            const float4 x1 = xa[2 * ks + 1];
            xf.b[0] = (__bf16)x0.x; xf.b[1] = (__bf16)x0.y;
            xf.b[2] = (__bf16)x0.z; xf.b[3] = (__bf16)x0.w;
            xf.b[4] = (__bf16)x1.x; xf.b[5] = (__bf16)x1.y;
            xf.b[6] = (__bf16)x1.z; xf.b[7] = (__bf16)x1.w;
            #pragma unroll
            for (int f = 0; f < 4; ++f) {
                const s8v wf = *reinterpret_cast<const s8v*>(
                    wt0 + (size_t)f * 16 * WT_LD + ks * 32);
                acc[f] = __builtin_amdgcn_mfma_f32_16x16x32_bf16(wf, xf.s, acc[f], 0, 0, 0);
            }
        }
        #pragma unroll
        for (int ks = 4; ks < 8; ++ks) {
            BF8 xf;
            const float4 x0 = xb[2 * (ks - 4)];
            const float4 x1 = xb[2 * (ks - 4) + 1];
            xf.b[0] = (__bf16)x0.x; xf.b[1] = (__bf16)x0.y;
            xf.b[2] = (__bf16)x0.z; xf.b[3] = (__bf16)x0.w;
            xf.b[4] = (__bf16)x1.x; xf.b[5] = (__bf16)x1.y;
            xf.b[6] = (__bf16)x1.z; xf.b[7] = (__bf16)x1.w;
            #pragma unroll
            for (int f = 0; f < 4; ++f) {
                const s8v wf = *reinterpret_cast<const s8v*>(
                    wt0 + (size_t)f * 16 * WT_LD + ks * 32);
                acc[f] = __builtin_amdgcn_mfma_f32_16x16x32_bf16(wf, xf.s, acc[f], 0, 0, 0);
            }
        }

        if (grow < n) {
            const float d = deg[grow];
            #pragma unroll
            for (int f = 0; f < 4; ++f) {
                ushort4 v;
                __bf16 b0 = (__bf16)(acc[f][0] * d);
                __bf16 b1 = (__bf16)(acc[f][1] * d);
                __bf16 b2 = (__bf16)(acc[f][2] * d);
                __bf16 b3 = (__bf16)(acc[f][3] * d);
                v.x = *reinterpret_cast<unsigned short*>(&b0);
                v.y = *reinterpret_cast<unsigned short*>(&b1);
                v.z = *reinterpret_cast<unsigned short*>(&b2);
                v.w = *reinterpret_cast<unsigned short*>(&b3);
                *reinterpret_cast<ushort4*>(
                    &Xp[(size_t)grow * D_OUT + f * 16 + kgrp * 4]) = v;
            }
        }
    }

    // ---- device-wide barrier (all 768 blocks co-resident) ----
    __threadfence();      // agent-scope release of Xp writes
    __syncthreads();
    if (tid == 0) {
        __hip_atomic_fetch_add(bar, 1u, __ATOMIC_ACQ_REL, __HIP_MEMORY_SCOPE_AGENT);
        while (__hip_atomic_load(bar, __ATOMIC_ACQUIRE, __HIP_MEMORY_SCOPE_AGENT)
               < (unsigned)gridDim.x)
            __builtin_amdgcn_s_sleep(1);
    }
    __syncthreads();
    __threadfence();      // acquire side

    // ---- phase 2: aggregation ----
    const int ngroups = (n + 31) / 32;
    const int nsub = tid >> 3;
    const int c8   = (tid & 7) * 8;

    for (int g = blockIdx.x; g < ngroups; g += gridDim.x) {
        const int node = g * 32 + nsub;
        if (node >= n) continue;

        const int e0 = rp[node];
        const int e1 = rp[node + 1];
        const int m  = e1 - e0;
        const float d = deg[node];

        float acc[8] = {};

        if (m == 16 && (e0 & 3) == 0) {
            int4 i4[4];
            #pragma unroll
            for (int b = 0; b < 4; ++b)
                i4[b] = *reinterpret_cast<const int4*>(&ci[e0 + b * 4]);
            const int idx[16] = { i4[0].x, i4[0].y, i4[0].z, i4[0].w,
                                  i4[1].x, i4[1].y, i4[1].z, i4[1].w,
                                  i4[2].x, i4[2].y, i4[2].z, i4[2].w,
                                  i4[3].x, i4[3].y, i4[3].z, i4[3].w };
            us8v v[16];
            #pragma unroll
            for (int j = 0; j < 16; ++j)
                v[j] = *reinterpret_cast<const us8v*>(&Xp[(size_t)idx[j] * D_OUT + c8]);
            #pragma unroll
            for (int j = 0; j < 16; ++j) {
                #pragma unroll
                for (int k = 0; k < 8; ++k)
                    acc[k] += __uint_as_float((unsigned)v[j][k] << 16);
            }
        } else {
            for (int e = e0; e < e1; ++e) {
                const us8v v = *reinterpret_cast<const us8v*>(&Xp[(size_t)ci[e] * D_OUT + c8]);
                #pragma unroll
                for (int k = 0; k < 8; ++k)
                    acc[k] += __uint_as_float((unsigned)v[k] << 16);
            }
        }

        float* op = out + (size_t)node * D_OUT + c8;
        *reinterpret_cast<float4*>(op)     = make_float4(acc[0]*d, acc[1]*d, acc[2]*d, acc[3]*d);
        *reinterpret_cast<float4*>(op + 4) = make_float4(acc[4]*d, acc[5]*d, acc[6]*d, acc[7]*d);
    }
}

extern "C" void kernel_launch(void* const* d_in, const int* in_sizes, int n_in,
                              void* d_out, int out_size, void* d_ws, size_t ws_size,
                              hipStream_t stream)
{
    const float* X   = (const float*)d_in[0];
    const float* W   = (const float*)d_in[1];
    const int*   rp  = (const int*)d_in[2];
    const int*   ci  = (const int*)d_in[3];
    const float* deg = (const float*)d_in[4];
    float* out = (float*)d_out;

    const int n = in_sizes[4];   // N_NODES

    unsigned short* Xp  = (unsigned short*)d_ws;                         // n*64 bf16 = 12.8 MB
    unsigned int*   bar = (unsigned int*)((char*)d_ws + (32u << 20));    // counter at +32MB

    hipMemsetAsync(bar, 0, sizeof(unsigned int), stream);   // capture-safe

    const int ntiles = (n + 15) / 16;   // 6250
    fused_gcn_kernel<<<NBLK, 256, 0, stream>>>(X, W, rp, ci, deg, Xp, out, bar, n, ntiles);
}

// Round 11
// 57.925 us; speedup vs baseline: 5.3440x; 5.3440x over previous
//
#include <hip/hip_runtime.h>
#include <hip/hip_bf16.h>

// GCN: out[i] = deg_i * sum_{j in N(i)} deg_j * (X@W)[j]
// K1 gemm: R7 body (W->LDS bf16 transposed, 2x8 pipelined X loads,
//          operand-swapped MFMA, fused deg_j, bf16 Xp) — but 782 blocks,
//          each wave handles 2 consecutive tiles (halves block preambles).
// K2 agg:  exact R2/R7 agg (measured ~25us, at random-gather ceiling).

constexpr int D_IN  = 256;
constexpr int D_OUT = 64;
constexpr int WT_LD = D_IN + 8;

typedef short  s8v  __attribute__((ext_vector_type(8)));
typedef __bf16 bf8v __attribute__((ext_vector_type(8)));
typedef float  f32x4 __attribute__((ext_vector_type(4)));
typedef unsigned short us8v __attribute__((ext_vector_type(8)));

union BF8 { bf8v b; s8v s; };

__global__ __launch_bounds__(256) void gemm_bf16_kernel(
    const float* __restrict__ X, const float* __restrict__ W,
    const float* __restrict__ deg, unsigned short* __restrict__ Xp,
    int n, int ntiles)
{
    __shared__ __bf16 Wt[D_OUT][WT_LD];

    const int tid = threadIdx.x;

    #pragma unroll
    for (int i = 0; i < 16; ++i) {
        const int f4 = tid + i * 256;
        const int k  = f4 >> 4;
        const int c4 = (f4 & 15) * 4;
        const float4 w = *reinterpret_cast<const float4*>(&W[(size_t)k * D_OUT + c4]);
        Wt[c4 + 0][k] = (__bf16)w.x;
        Wt[c4 + 1][k] = (__bf16)w.y;
        Wt[c4 + 2][k] = (__bf16)w.z;
        Wt[c4 + 3][k] = (__bf16)w.w;
    }
    __syncthreads();

    const int wid  = tid >> 6;
    const int lane = tid & 63;
    const int lrow = lane & 15;
    const int kgrp = lane >> 4;

    const __bf16* wt0 = &Wt[lrow][kgrp * 8];
    const int tile0 = (blockIdx.x * 4 + wid) * 2;

    #pragma unroll
    for (int t = 0; t < 2; ++t) {
        const int tile = tile0 + t;
        if (tile >= ntiles) break;

        const int grow = tile * 16 + lrow;
        const int xr   = grow < n ? grow : n - 1;
        const float* xrow = X + (size_t)xr * D_IN + kgrp * 8;

        // ---- R7 software pipeline: two 8-load halves ----
        float4 xa[8], xb[8];
        #pragma unroll
        for (int k = 0; k < 4; ++k) {
            xa[2 * k]     = *reinterpret_cast<const float4*>(xrow + k * 32);
            xa[2 * k + 1] = *reinterpret_cast<const float4*>(xrow + k * 32 + 4);
        }
        #pragma unroll
        for (int k = 0; k < 4; ++k) {
            xb[2 * k]     = *reinterpret_cast<const float4*>(xrow + (k + 4) * 32);
            xb[2 * k + 1] = *reinterpret_cast<const float4*>(xrow + (k + 4) * 32 + 4);
        }

        f32x4 acc[4] = {};

        #pragma unroll
        for (int ks = 0; ks < 4; ++ks) {         // consume A (B in flight)
            BF8 xf;
            const float4 x0 = xa[2 * ks];
            const float4 x1 = xa[2 * ks + 1];
            xf.b[0] = (__bf16)x0.x; xf.b[1] = (__bf16)x0.y;
            xf.b[2] = (__bf16)x0.z; xf.b[3] = (__bf16)x0.w;
            xf.b[4] = (__bf16)x1.x; xf.b[5] = (__bf16)x1.y;
            xf.b[6] = (__bf16)x1.z; xf.b[7] = (__bf16)x1.w;
            #pragma unroll
            for (int f = 0; f < 4; ++f) {
                const s8v wf = *reinterpret_cast<const s8v*>(
                    wt0 + (size_t)f * 16 * WT_LD + ks * 32);
                acc[f] = __builtin_amdgcn_mfma_f32_16x16x32_bf16(wf, xf.s, acc[f], 0, 0, 0);
            }
        }
        #pragma unroll
        for (int ks = 4; ks < 8; ++ks) {         // consume B
            BF8 xf;
            const float4 x0 = xb[2 * (ks - 4)];
            const float4 x1 = xb[2 * (ks - 4) + 1];
            xf.b[0] = (__bf16)x0.x; xf.b[1] = (__bf16)x0.y;
            xf.b[2] = (__bf16)x0.z; xf.b[3] = (__bf16)x0.w;
            xf.b[4] = (__bf16)x1.x; xf.b[5] = (__bf16)x1.y;
            xf.b[6] = (__bf16)x1.z; xf.b[7] = (__bf16)x1.w;
            #pragma unroll
            for (int f = 0; f < 4; ++f) {
                const s8v wf = *reinterpret_cast<const s8v*>(
                    wt0 + (size_t)f * 16 * WT_LD + ks * 32);
                acc[f] = __builtin_amdgcn_mfma_f32_16x16x32_bf16(wf, xf.s, acc[f], 0, 0, 0);
            }
        }

        if (grow < n) {
            const float d = deg[grow];
            #pragma unroll
            for (int f = 0; f < 4; ++f) {
                ushort4 v;
                __bf16 b0 = (__bf16)(acc[f][0] * d);
                __bf16 b1 = (__bf16)(acc[f][1] * d);
                __bf16 b2 = (__bf16)(acc[f][2] * d);
                __bf16 b3 = (__bf16)(acc[f][3] * d);
                v.x = *reinterpret_cast<unsigned short*>(&b0);
                v.y = *reinterpret_cast<unsigned short*>(&b1);
                v.z = *reinterpret_cast<unsigned short*>(&b2);
                v.w = *reinterpret_cast<unsigned short*>(&b3);
                *reinterpret_cast<ushort4*>(
                    &Xp[(size_t)grow * D_OUT + f * 16 + kgrp * 4]) = v;
            }
        }
    }
}

__global__ __launch_bounds__(256) void agg_kernel(
    const unsigned short* __restrict__ Xp, const int* __restrict__ rp,
    const int* __restrict__ ci, const float* __restrict__ deg,
    float* __restrict__ out, int n)
{
    const int node = blockIdx.x * 32 + (threadIdx.x >> 3);
    if (node >= n) return;
    const int c8 = (threadIdx.x & 7) * 8;

    const int e0 = rp[node];
    const int e1 = rp[node + 1];
    const int m  = e1 - e0;
    const float d = deg[node];

    float acc[8] = {};

    if (m == 16 && (e0 & 3) == 0) {
        int4 i4[4];
        #pragma unroll
        for (int b = 0; b < 4; ++b)
            i4[b] = *reinterpret_cast<const int4*>(&ci[e0 + b * 4]);
        const int idx[16] = { i4[0].x, i4[0].y, i4[0].z, i4[0].w,
                              i4[1].x, i4[1].y, i4[1].z, i4[1].w,
                              i4[2].x, i4[2].y, i4[2].z, i4[2].w,
                              i4[3].x, i4[3].y, i4[3].z, i4[3].w };
        us8v v[16];
        #pragma unroll
        for (int j = 0; j < 16; ++j)
            v[j] = *reinterpret_cast<const us8v*>(&Xp[(size_t)idx[j] * D_OUT + c8]);
        #pragma unroll
        for (int j = 0; j < 16; ++j) {
            #pragma unroll
            for (int k = 0; k < 8; ++k)
                acc[k] += __uint_as_float((unsigned)v[j][k] << 16);
        }
    } else {
        for (int e = e0; e < e1; ++e) {
            const us8v v = *reinterpret_cast<const us8v*>(&Xp[(size_t)ci[e] * D_OUT + c8]);
            #pragma unroll
            for (int k = 0; k < 8; ++k)
                acc[k] += __uint_as_float((unsigned)v[k] << 16);
        }
    }

    float* op = out + (size_t)node * D_OUT + c8;
    *reinterpret_cast<float4*>(op)     = make_float4(acc[0]*d, acc[1]*d, acc[2]*d, acc[3]*d);
    *reinterpret_cast<float4*>(op + 4) = make_float4(acc[4]*d, acc[5]*d, acc[6]*d, acc[7]*d);
}

extern "C" void kernel_launch(void* const* d_in, const int* in_sizes, int n_in,
                              void* d_out, int out_size, void* d_ws, size_t ws_size,
                              hipStream_t stream)
{
    const float* X   = (const float*)d_in[0];
    const float* W   = (const float*)d_in[1];
    const int*   rp  = (const int*)d_in[2];
    const int*   ci  = (const int*)d_in[3];
    const float* deg = (const float*)d_in[4];
    float* out = (float*)d_out;
    unsigned short* Xp = (unsigned short*)d_ws;

    const int n = in_sizes[4];

    const int ntiles = (n + 15) / 16;                 // 6250
    const int gemm_blocks = (ntiles + 7) / 8;         // 782: 8 tiles/block, 2/wave
    gemm_bf16_kernel<<<gemm_blocks, 256, 0, stream>>>(X, W, deg, Xp, n, ntiles);

    const int agg_blocks = (n + 31) / 32;
    agg_kernel<<<agg_blocks, 256, 0, stream>>>(Xp, rp, ci, deg, out, n);
}

// Round 13
// 56.341 us; speedup vs baseline: 5.4943x; 1.0281x over previous
//
#include <hip/hip_runtime.h>
#include <hip/hip_bf16.h>

// GCN: out[i] = deg_i * sum_{j in N(i)} deg_j * (X@W)[j]
// R7 structure + cache-pollution control (NT via ext_vector types):
//   - GEMM Xp stores nontemporal (re-read only cross-XCD via L3)
//   - agg `out` stores nontemporal (never re-read; keep L2 for Xp gathers)
//   - agg `ci` loads nontemporal (read-once stream)

constexpr int D_IN  = 256;
constexpr int D_OUT = 64;
constexpr int WT_LD = D_IN + 8;

typedef short  s8v  __attribute__((ext_vector_type(8)));
typedef __bf16 bf8v __attribute__((ext_vector_type(8)));
typedef float  f32x4 __attribute__((ext_vector_type(4)));
typedef unsigned short us8v __attribute__((ext_vector_type(8)));
typedef unsigned short us4v __attribute__((ext_vector_type(4)));
typedef int    i32x4 __attribute__((ext_vector_type(4)));

union BF8 { bf8v b; s8v s; };

__global__ __launch_bounds__(256) void gemm_bf16_kernel(
    const float* __restrict__ X, const float* __restrict__ W,
    const float* __restrict__ deg, unsigned short* __restrict__ Xp, int n)
{
    __shared__ __bf16 Wt[D_OUT][WT_LD];

    const int tid = threadIdx.x;

    #pragma unroll
    for (int i = 0; i < 16; ++i) {
        const int f4 = tid + i * 256;
        const int k  = f4 >> 4;
        const int c4 = (f4 & 15) * 4;
        const float4 w = *reinterpret_cast<const float4*>(&W[(size_t)k * D_OUT + c4]);
        Wt[c4 + 0][k] = (__bf16)w.x;
        Wt[c4 + 1][k] = (__bf16)w.y;
        Wt[c4 + 2][k] = (__bf16)w.z;
        Wt[c4 + 3][k] = (__bf16)w.w;
    }
    __syncthreads();

    const int wid  = tid >> 6;
    const int lane = tid & 63;
    const int lrow = lane & 15;
    const int kgrp = lane >> 4;

    const int row0 = blockIdx.x * 64 + wid * 16;
    if (row0 >= n) return;
    const int grow = row0 + lrow;
    const int xr   = grow < n ? grow : n - 1;

    const __bf16* wt0 = &Wt[lrow][kgrp * 8];
    const float* xrow = X + (size_t)xr * D_IN + kgrp * 8;

    // ---- software pipeline: two 8-load halves ----
    float4 xa[8], xb[8];
    #pragma unroll
    for (int k = 0; k < 4; ++k) {
        xa[2 * k]     = *reinterpret_cast<const float4*>(xrow + k * 32);
        xa[2 * k + 1] = *reinterpret_cast<const float4*>(xrow + k * 32 + 4);
    }
    #pragma unroll
    for (int k = 0; k < 4; ++k) {
        xb[2 * k]     = *reinterpret_cast<const float4*>(xrow + (k + 4) * 32);
        xb[2 * k + 1] = *reinterpret_cast<const float4*>(xrow + (k + 4) * 32 + 4);
    }

    f32x4 acc[4] = {};

    #pragma unroll
    for (int ks = 0; ks < 4; ++ks) {         // consume A (B in flight)
        BF8 xf;
        const float4 x0 = xa[2 * ks];
        const float4 x1 = xa[2 * ks + 1];
        xf.b[0] = (__bf16)x0.x; xf.b[1] = (__bf16)x0.y;
        xf.b[2] = (__bf16)x0.z; xf.b[3] = (__bf16)x0.w;
        xf.b[4] = (__bf16)x1.x; xf.b[5] = (__bf16)x1.y;
        xf.b[6] = (__bf16)x1.z; xf.b[7] = (__bf16)x1.w;
        #pragma unroll
        for (int f = 0; f < 4; ++f) {
            const s8v wf = *reinterpret_cast<const s8v*>(
                wt0 + (size_t)f * 16 * WT_LD + ks * 32);
            acc[f] = __builtin_amdgcn_mfma_f32_16x16x32_bf16(wf, xf.s, acc[f], 0, 0, 0);
        }
    }
    #pragma unroll
    for (int ks = 4; ks < 8; ++ks) {         // consume B
        BF8 xf;
        const float4 x0 = xb[2 * (ks - 4)];
        const float4 x1 = xb[2 * (ks - 4) + 1];
        xf.b[0] = (__bf16)x0.x; xf.b[1] = (__bf16)x0.y;
        xf.b[2] = (__bf16)x0.z; xf.b[3] = (__bf16)x0.w;
        xf.b[4] = (__bf16)x1.x; xf.b[5] = (__bf16)x1.y;
        xf.b[6] = (__bf16)x1.z; xf.b[7] = (__bf16)x1.w;
        #pragma unroll
        for (int f = 0; f < 4; ++f) {
            const s8v wf = *reinterpret_cast<const s8v*>(
                wt0 + (size_t)f * 16 * WT_LD + ks * 32);
            acc[f] = __builtin_amdgcn_mfma_f32_16x16x32_bf16(wf, xf.s, acc[f], 0, 0, 0);
        }
    }

    if (grow < n) {
        const float d = deg[grow];
        #pragma unroll
        for (int f = 0; f < 4; ++f) {
            us4v v;
            __bf16 b0 = (__bf16)(acc[f][0] * d);
            __bf16 b1 = (__bf16)(acc[f][1] * d);
            __bf16 b2 = (__bf16)(acc[f][2] * d);
            __bf16 b3 = (__bf16)(acc[f][3] * d);
            v[0] = *reinterpret_cast<unsigned short*>(&b0);
            v[1] = *reinterpret_cast<unsigned short*>(&b1);
            v[2] = *reinterpret_cast<unsigned short*>(&b2);
            v[3] = *reinterpret_cast<unsigned short*>(&b3);
            // NT: re-read only by other XCDs via L3; skip local-L2 dirty phase
            __builtin_nontemporal_store(v,
                reinterpret_cast<us4v*>(&Xp[(size_t)grow * D_OUT + f * 16 + kgrp * 4]));
        }
    }
}

__global__ __launch_bounds__(256) void agg_kernel(
    const unsigned short* __restrict__ Xp, const int* __restrict__ rp,
    const int* __restrict__ ci, const float* __restrict__ deg,
    float* __restrict__ out, int n)
{
    const int node = blockIdx.x * 32 + (threadIdx.x >> 3);
    if (node >= n) return;
    const int c8 = (threadIdx.x & 7) * 8;

    const int e0 = rp[node];
    const int e1 = rp[node + 1];
    const int m  = e1 - e0;
    const float d = deg[node];

    float acc[8] = {};

    if (m == 16 && (e0 & 3) == 0) {
        i32x4 i4[4];
        #pragma unroll
        for (int b = 0; b < 4; ++b)
            i4[b] = __builtin_nontemporal_load(
                reinterpret_cast<const i32x4*>(&ci[e0 + b * 4]));
        const int idx[16] = { i4[0][0], i4[0][1], i4[0][2], i4[0][3],
                              i4[1][0], i4[1][1], i4[1][2], i4[1][3],
                              i4[2][0], i4[2][1], i4[2][2], i4[2][3],
                              i4[3][0], i4[3][1], i4[3][2], i4[3][3] };
        us8v v[16];
        #pragma unroll
        for (int j = 0; j < 16; ++j)
            v[j] = *reinterpret_cast<const us8v*>(&Xp[(size_t)idx[j] * D_OUT + c8]);
        #pragma unroll
        for (int j = 0; j < 16; ++j) {
            #pragma unroll
            for (int k = 0; k < 8; ++k)
                acc[k] += __uint_as_float((unsigned)v[j][k] << 16);
        }
    } else {
        for (int e = e0; e < e1; ++e) {
            const us8v v = *reinterpret_cast<const us8v*>(&Xp[(size_t)ci[e] * D_OUT + c8]);
            #pragma unroll
            for (int k = 0; k < 8; ++k)
                acc[k] += __uint_as_float((unsigned)v[k] << 16);
        }
    }

    float* op = out + (size_t)node * D_OUT + c8;
    // NT: out is never re-read — don't let 25.6MB of stores evict Xp from L2
    f32x4 o0 = { acc[0]*d, acc[1]*d, acc[2]*d, acc[3]*d };
    f32x4 o1 = { acc[4]*d, acc[5]*d, acc[6]*d, acc[7]*d };
    __builtin_nontemporal_store(o0, reinterpret_cast<f32x4*>(op));
    __builtin_nontemporal_store(o1, reinterpret_cast<f32x4*>(op + 4));
}

extern "C" void kernel_launch(void* const* d_in, const int* in_sizes, int n_in,
                              void* d_out, int out_size, void* d_ws, size_t ws_size,
                              hipStream_t stream)
{
    const float* X   = (const float*)d_in[0];
    const float* W   = (const float*)d_in[1];
    const int*   rp  = (const int*)d_in[2];
    const int*   ci  = (const int*)d_in[3];
    const float* deg = (const float*)d_in[4];
    float* out = (float*)d_out;
    unsigned short* Xp = (unsigned short*)d_ws;

    const int n = in_sizes[4];

    const int gemm_blocks = (n + 63) / 64;
    gemm_bf16_kernel<<<gemm_blocks, 256, 0, stream>>>(X, W, deg, Xp, n);

    const int agg_blocks = (n + 31) / 32;
    agg_kernel<<<agg_blocks, 256, 0, stream>>>(Xp, rp, ci, deg, out, n);
}